// Round 5
// baseline (204.430 us; speedup 1.0000x reference)
//
#include <hip/hip_runtime.h>
#include <math.h>

#define D_MELS 80
#define T_DIM  4000
#define NQ     10
#define NTHR   256
#define RPI    14          // rows CONTRIBUTED per tile (16 loaded, 2 overlap)

// quantities: 0=l1 1=band 2=diff2 3=tgt2 4=energy 5=mask 6=delta 7=dmask 8=delta2 9=d2mask

// __launch_bounds__(256, 8): 8 waves/EU min -> VGPR capped at 64 -> 8 waves/SIMD
// eligible (vs 4 at VGPR=68, the R3 occupancy cliff). TLP across waves is the
// latency-hiding mechanism for this kernel (R4 falsified per-wave pipelining).
__global__ __launch_bounds__(NTHR, 8) void mel_loss_main(
    const float* __restrict__ pred, const float* __restrict__ tgt,
    const float* __restrict__ mask,
    float* __restrict__ partial, int BT, int Jtot, int nblk)
{
    const int tid  = threadIdx.x;
    const int lane = tid & 63;
    const int qtr  = lane & 3;        // float4-quarter of row (5 float4s per lane)
    const int rw   = lane >> 2;       // row within 16-row tile
    const int gw   = blockIdx.x * (NTHR / 64) + (tid >> 6);

    const float4* p4 = (const float4*)pred;
    const float4* q4 = (const float4*)tgt;
    const int lsrc4 = (lane - 4) & 63;   // lane holding row r-1 (same qtr)
    const int lsrc8 = (lane - 8) & 63;   // lane holding row r-2 (same qtr)

    float v_l1 = 0.f, v_band = 0.f, v_diff2 = 0.f, v_tgt2 = 0.f, v_energy = 0.f;
    float v_m = 0.f, v_d = 0.f, v_dm = 0.f, v_d2 = 0.f, v_d2m = 0.f;

    const int j0 = gw * 2;               // K = 2 tiles per wave

    // clamped lane row for tile s
    int r0 = j0 * RPI - 2 + rw;
    int r1 = r0 + RPI;
    int rl0 = r0 < 0 ? 0 : (r0 >= BT ? BT - 1 : r0);
    int rl1 = r1 < 0 ? 0 : (r1 >= BT ? BT - 1 : r1);

    // hoist BOTH mask loads (independent; removes one mask->data serialization)
    float mv0 = (j0     < Jtot) ? mask[rl0] : 0.f;
    float mv1 = (j0 + 1 < Jtot) ? mask[rl1] : 0.f;

    #pragma unroll
    for (int s = 0; s < 2; ++s) {
        const int r     = s ? r1  : r0;
        const int rload = s ? rl1 : rl0;
        const float mload = s ? mv1 : mv0;

        // dead-tile skip: every loss term touching row r carries mask[r];
        // dead rows cluster in sequence tails -> wave-uniform branch.
        if (!__any(mload != 0.0f)) continue;

        const int t = rload % T_DIM;          // for contributing rows, rload == r
        const float4* pr = p4 + (size_t)rload * (D_MELS / 4) + qtr;
        const float4* qr = q4 + (size_t)rload * (D_MELS / 4) + qtr;

        const float m1 = __shfl(mload, lsrc4, 64);   // mask[r-1] (valid where used)
        const float m2 = __shfl(mload, lsrc8, 64);   // mask[r-2]
        const bool contrib = (rw >= 2) && (r < BT);
        const float mt   = contrib ? mload : 0.f;
        const float dmv  = (t >= 1) ? mt * m1 : 0.f; // t-gating kills seq-boundary garbage
        const float d2mv = (t >= 2) ? dmv * m2 : 0.f;

        float l1r = 0.f, frr = 0.f, sqr = 0.f, t2r = 0.f, er = 0.f, dr = 0.f, d2r = 0.f;

        #pragma unroll
        for (int k = 0; k < 5; ++k) {
            float4 p = pr[4 * k];
            float4 q = qr[4 * k];
            float e0 = p.x - q.x, e1 = p.y - q.y, e2 = p.z - q.z, e3 = p.w - q.w;

            // e of row r-1 / r-2 live in neighbor lanes of THIS tile — no reload
            float f0 = __shfl(e0, lsrc4, 64);
            float f1 = __shfl(e1, lsrc4, 64);
            float f2 = __shfl(e2, lsrc4, 64);
            float f3 = __shfl(e3, lsrc4, 64);
            float g0 = __shfl(e0, lsrc8, 64);
            float g1 = __shfl(e1, lsrc8, 64);
            float g2 = __shfl(e2, lsrc8, 64);
            float g3 = __shfl(e3, lsrc8, 64);

            float a0 = fabsf(e0), a1 = fabsf(e1), a2 = fabsf(e2), a3 = fabsf(e3);
            float ak = a0 + a1 + a2 + a3;
            l1r += ak;
            // band extra weight (+1) on d in [10,50); d = 16k + 4*qtr + c (branchy: no sel regs)
            if (k == 1 || k == 2) frr += ak;
            else if (k == 0)      frr += (qtr == 2) ? (a2 + a3) : ((qtr == 3) ? ak : 0.f);
            else if (k == 3)      frr += (qtr == 0) ? (a0 + a1) : 0.f;

            sqr += e0 * e0 + e1 * e1 + e2 * e2 + e3 * e3;
            t2r += q.x * q.x + q.y * q.y + q.z * q.z + q.w * q.w;
            er  += e0 + e1 + e2 + e3;
            dr  += fabsf(e0 - f0) + fabsf(e1 - f1) + fabsf(e2 - f2) + fabsf(e3 - f3);
            d2r += fabsf(e0 - 2.f * f0 + g0) + fabsf(e1 - 2.f * f1 + g1)
                 + fabsf(e2 - 2.f * f2 + g2) + fabsf(e3 - 2.f * f3 + g3);
        }

        v_l1    += l1r * mt;
        v_band  += (l1r + frr) * mt;
        v_diff2 += sqr * mt;
        v_tgt2  += t2r * mt;
        v_d     += dr * dmv;
        v_d2    += d2r * d2mv;

        // row-sum of e within the quad (qtr 0..3 share rw)
        er += __shfl_xor(er, 1, 64);
        er += __shfl_xor(er, 2, 64);
        if (qtr == 0) {
            v_energy += fabsf(er) * mt;
            v_m   += mt;
            v_dm  += dmv;
            v_d2m += d2mv;
        }
    }

    // ---- block reduction: wave shuffle -> LDS -> per-block store (NO atomics) ----
    float vals[NQ] = {v_l1, v_band, v_diff2, v_tgt2, v_energy,
                      v_m, v_d, v_dm, v_d2, v_d2m};
    #pragma unroll
    for (int q = 0; q < NQ; ++q) {
        float v = vals[q];
        #pragma unroll
        for (int off = 32; off > 0; off >>= 1)
            v += __shfl_down(v, off, 64);
        vals[q] = v;
    }
    __shared__ float red[NTHR / 64][NQ];
    int wave = tid >> 6;
    if (lane == 0) {
        #pragma unroll
        for (int q = 0; q < NQ; ++q) red[wave][q] = vals[q];
    }
    __syncthreads();
    if (tid < NQ) {
        float s = 0.f;
        #pragma unroll
        for (int wv2 = 0; wv2 < NTHR / 64; ++wv2) s += red[wv2][tid];
        partial[tid * nblk + blockIdx.x] = s;
    }
}

__global__ __launch_bounds__(640) void mel_loss_finalize(
    const float* __restrict__ partial, const float* __restrict__ w,
    float* __restrict__ out, int nblk)
{
    const int tid = threadIdx.x;
    const int wv  = tid >> 6;        // quantity index 0..9
    const int lane = tid & 63;
    __shared__ float fin[NQ];

    float s = 0.f;
    for (int i = lane; i < nblk; i += 64) s += partial[wv * nblk + i];
    #pragma unroll
    for (int off = 32; off > 0; off >>= 1) s += __shfl_down(s, off, 64);
    if (lane == 0 && wv < NQ) fin[wv] = s;
    __syncthreads();

    if (tid == 0) {
        float l1s = fin[0], bands = fin[1], diff2 = fin[2], tgt2 = fin[3];
        float energys = fin[4], ms = fin[5], ds = fin[6], dms = fin[7];
        float d2s = fin[8], d2ms = fin[9];

        float wsum = 0.f;
        for (int d = 0; d < D_MELS; ++d) wsum += w[d];
        float wmean = wsum / (float)D_MELS;

        float n1  = fmaxf(ms   * (float)D_MELS, 1.f);
        float nd  = fmaxf(dms  * (float)D_MELS, 1.f);
        float nd2 = fmaxf(d2ms * (float)D_MELS, 1.f);

        float l1_loss     = l1s / n1;
        float delta_loss  = ds / nd;
        float delta2_loss = d2s / nd2;
        float sc_num = sqrtf(diff2 / n1);
        float sc_den = fmaxf(sqrtf(tgt2 / n1), 1e-8f);
        float sc_loss = sc_num / sc_den;
        float band_loss = (bands / n1) / wmean;
        float energy_loss = (energys / (float)D_MELS) / fmaxf(ms, 1.f);

        out[0] = 1.0f * l1_loss + 0.5f * delta_loss + 0.25f * delta2_loss
               + 0.5f * sc_loss + 1.0f * band_loss + 0.5f * energy_loss;
    }
}

extern "C" void kernel_launch(void* const* d_in, const int* in_sizes, int n_in,
                              void* d_out, int out_size, void* d_ws, size_t ws_size,
                              hipStream_t stream) {
    const float* pred = (const float*)d_in[0];
    const float* tgt  = (const float*)d_in[1];
    const float* mask = (const float*)d_in[2];
    const float* w    = (const float*)d_in[3];
    int BT = in_sizes[2];                     // B*T = 256000
    float* partial = (float*)d_ws;            // NQ * grid floats

    int Jtot = (BT + RPI - 1) / RPI;          // 18286 14-row tiles
    int nwaves = (Jtot + 1) / 2;              // K = 2 tiles per wave
    int grid = (nwaves + (NTHR / 64) - 1) / (NTHR / 64);   // 2286

    mel_loss_main<<<grid, NTHR, 0, stream>>>(pred, tgt, mask, partial, BT, Jtot, grid);
    mel_loss_finalize<<<1, 640, 0, stream>>>(partial, w, (float*)d_out, grid);
}

// Round 6
// 194.565 us; speedup vs baseline: 1.0507x; 1.0507x over previous
//
#include <hip/hip_runtime.h>
#include <math.h>

#define D_MELS 80
#define T_DIM  4000
#define NQ     10
#define NTHR   256
#define RPI    14          // rows CONTRIBUTED per tile (16 loaded, 2 overlap)

// quantities: 0=l1 1=band 2=diff2 3=tgt2 4=energy 5=mask 6=delta 7=dmask 8=delta2 9=d2mask

// __launch_bounds__(256, 8): target 8 waves/SIMD (the VGPR<=64 HW cliff).
// R5 showed the compiler spills if true liveness >64 — so the k-loop below is
// deliberately NOT unrolled: one (p,q) float4 pair live at a time (8 regs)
// instead of all ten (40 regs). TLP across 32 waves/CU replaces per-wave MLP
// (R5 measured: occupancy 59.7% -> 2.0 TB/s delivery; Little's law needs only
// ~3.5 KB/CU in flight at 2.4 TB/s, 32 waves x 2 loads x 1KB >> that).
__global__ __launch_bounds__(NTHR, 8) void mel_loss_main(
    const float* __restrict__ pred, const float* __restrict__ tgt,
    const float* __restrict__ mask,
    float* __restrict__ partial, int BT, int Jtot, int nblk)
{
    const int tid  = threadIdx.x;
    const int lane = tid & 63;
    const int qtr  = lane & 3;        // float4-quarter of row (5 float4s per lane)
    const int rw   = lane >> 2;       // row within 16-row tile
    const int gw   = blockIdx.x * (NTHR / 64) + (tid >> 6);

    const float4* p4 = (const float4*)pred;
    const float4* q4 = (const float4*)tgt;
    const int lsrc4 = (lane - 4) & 63;   // lane holding row r-1 (same qtr)
    const int lsrc8 = (lane - 8) & 63;   // lane holding row r-2 (same qtr)

    float v_l1 = 0.f, v_band = 0.f, v_diff2 = 0.f, v_tgt2 = 0.f, v_energy = 0.f;
    float v_m = 0.f, v_d = 0.f, v_dm = 0.f, v_d2 = 0.f, v_d2m = 0.f;

    const int j0 = gw * 2;               // K = 2 tiles per wave
    const int r0 = j0 * RPI - 2 + rw;

    // hoist BOTH mask loads (independent; removes mask->data serialization)
    int rl0 = r0 < 0 ? 0 : (r0 >= BT ? BT - 1 : r0);
    int rtmp = r0 + RPI;
    int rl1 = rtmp < 0 ? 0 : (rtmp >= BT ? BT - 1 : rtmp);
    float mv0 = (j0     < Jtot) ? mask[rl0] : 0.f;
    float mv1 = (j0 + 1 < Jtot) ? mask[rl1] : 0.f;

    #pragma unroll
    for (int s = 0; s < 2; ++s) {
        const int r = r0 + s * RPI;
        const float mload = s ? mv1 : mv0;

        // dead-tile skip: every loss term touching row r carries mask[r];
        // dead rows cluster in sequence tails -> wave-uniform branch.
        if (!__any(mload != 0.0f)) continue;

        const int rload = r < 0 ? 0 : (r >= BT ? BT - 1 : r);
        const int t = rload % T_DIM;          // for contributing rows, rload == r

        const float4* pr = p4 + (size_t)rload * (D_MELS / 4) + qtr;
        const float4* qr = q4 + (size_t)rload * (D_MELS / 4) + qtr;

        const float m1 = __shfl(mload, lsrc4, 64);   // mask[r-1] (valid where used)
        const float m2 = __shfl(mload, lsrc8, 64);   // mask[r-2]
        const bool contrib = (rw >= 2) && (r < BT);
        const float mt   = contrib ? mload : 0.f;
        const float dmv  = (t >= 1) ? mt * m1 : 0.f; // t-gating kills seq-boundary garbage
        const float d2mv = (t >= 2) ? dmv * m2 : 0.f;

        float l1r = 0.f, frr = 0.f, sqr = 0.f, t2r = 0.f, er = 0.f, dr = 0.f, d2r = 0.f;

        #pragma unroll 1   // keep ONE float4 pair live: reg pressure, not MLP, is the binding constraint
        for (int k = 0; k < 5; ++k) {
            float4 p = pr[4 * k];
            float4 q = qr[4 * k];
            float e0 = p.x - q.x, e1 = p.y - q.y, e2 = p.z - q.z, e3 = p.w - q.w;

            // e of row r-1 / r-2 live in neighbor lanes of THIS tile — no reload
            float f0 = __shfl(e0, lsrc4, 64);
            float f1 = __shfl(e1, lsrc4, 64);
            float f2 = __shfl(e2, lsrc4, 64);
            float f3 = __shfl(e3, lsrc4, 64);
            float g0 = __shfl(e0, lsrc8, 64);
            float g1 = __shfl(e1, lsrc8, 64);
            float g2 = __shfl(e2, lsrc8, 64);
            float g3 = __shfl(e3, lsrc8, 64);

            float a0 = fabsf(e0), a1 = fabsf(e1), a2 = fabsf(e2), a3 = fabsf(e3);
            l1r += a0 + a1 + a2 + a3;

            // band extra (+1) on d in [10,50); d = 16k + 4qtr + c, branchless range test
            const int d0 = (k << 4) + (qtr << 2);
            frr += ((unsigned)(d0 + 0 - 10) < 40u ? a0 : 0.f)
                 + ((unsigned)(d0 + 1 - 10) < 40u ? a1 : 0.f)
                 + ((unsigned)(d0 + 2 - 10) < 40u ? a2 : 0.f)
                 + ((unsigned)(d0 + 3 - 10) < 40u ? a3 : 0.f);

            sqr += e0 * e0 + e1 * e1 + e2 * e2 + e3 * e3;
            t2r += q.x * q.x + q.y * q.y + q.z * q.z + q.w * q.w;
            er  += e0 + e1 + e2 + e3;
            dr  += fabsf(e0 - f0) + fabsf(e1 - f1) + fabsf(e2 - f2) + fabsf(e3 - f3);
            d2r += fabsf(e0 - 2.f * f0 + g0) + fabsf(e1 - 2.f * f1 + g1)
                 + fabsf(e2 - 2.f * f2 + g2) + fabsf(e3 - 2.f * f3 + g3);
        }

        v_l1    += l1r * mt;
        v_band  += (l1r + frr) * mt;
        v_diff2 += sqr * mt;
        v_tgt2  += t2r * mt;
        v_d     += dr * dmv;
        v_d2    += d2r * d2mv;

        // row-sum of e within the quad (qtr 0..3 share rw)
        er += __shfl_xor(er, 1, 64);
        er += __shfl_xor(er, 2, 64);
        if (qtr == 0) {
            v_energy += fabsf(er) * mt;
            v_m   += mt;
            v_dm  += dmv;
            v_d2m += d2mv;
        }
    }

    // ---- block reduction: wave shuffle -> LDS -> per-block store (NO atomics) ----
    float vals[NQ] = {v_l1, v_band, v_diff2, v_tgt2, v_energy,
                      v_m, v_d, v_dm, v_d2, v_d2m};
    #pragma unroll
    for (int q = 0; q < NQ; ++q) {
        float v = vals[q];
        #pragma unroll
        for (int off = 32; off > 0; off >>= 1)
            v += __shfl_down(v, off, 64);
        vals[q] = v;
    }
    __shared__ float red[NTHR / 64][NQ];
    int wave = tid >> 6;
    if (lane == 0) {
        #pragma unroll
        for (int q = 0; q < NQ; ++q) red[wave][q] = vals[q];
    }
    __syncthreads();
    if (tid < NQ) {
        float s = 0.f;
        #pragma unroll
        for (int wv2 = 0; wv2 < NTHR / 64; ++wv2) s += red[wv2][tid];
        partial[tid * nblk + blockIdx.x] = s;
    }
}

__global__ __launch_bounds__(640) void mel_loss_finalize(
    const float* __restrict__ partial, const float* __restrict__ w,
    float* __restrict__ out, int nblk)
{
    const int tid = threadIdx.x;
    const int wv  = tid >> 6;        // quantity index 0..9
    const int lane = tid & 63;
    __shared__ float fin[NQ];

    float s = 0.f;
    for (int i = lane; i < nblk; i += 64) s += partial[wv * nblk + i];
    #pragma unroll
    for (int off = 32; off > 0; off >>= 1) s += __shfl_down(s, off, 64);
    if (lane == 0 && wv < NQ) fin[wv] = s;
    __syncthreads();

    if (tid == 0) {
        float l1s = fin[0], bands = fin[1], diff2 = fin[2], tgt2 = fin[3];
        float energys = fin[4], ms = fin[5], ds = fin[6], dms = fin[7];
        float d2s = fin[8], d2ms = fin[9];

        float wsum = 0.f;
        for (int d = 0; d < D_MELS; ++d) wsum += w[d];
        float wmean = wsum / (float)D_MELS;

        float n1  = fmaxf(ms   * (float)D_MELS, 1.f);
        float nd  = fmaxf(dms  * (float)D_MELS, 1.f);
        float nd2 = fmaxf(d2ms * (float)D_MELS, 1.f);

        float l1_loss     = l1s / n1;
        float delta_loss  = ds / nd;
        float delta2_loss = d2s / nd2;
        float sc_num = sqrtf(diff2 / n1);
        float sc_den = fmaxf(sqrtf(tgt2 / n1), 1e-8f);
        float sc_loss = sc_num / sc_den;
        float band_loss = (bands / n1) / wmean;
        float energy_loss = (energys / (float)D_MELS) / fmaxf(ms, 1.f);

        out[0] = 1.0f * l1_loss + 0.5f * delta_loss + 0.25f * delta2_loss
               + 0.5f * sc_loss + 1.0f * band_loss + 0.5f * energy_loss;
    }
}

extern "C" void kernel_launch(void* const* d_in, const int* in_sizes, int n_in,
                              void* d_out, int out_size, void* d_ws, size_t ws_size,
                              hipStream_t stream) {
    const float* pred = (const float*)d_in[0];
    const float* tgt  = (const float*)d_in[1];
    const float* mask = (const float*)d_in[2];
    const float* w    = (const float*)d_in[3];
    int BT = in_sizes[2];                     // B*T = 256000
    float* partial = (float*)d_ws;            // NQ * grid floats

    int Jtot = (BT + RPI - 1) / RPI;          // 18286 14-row tiles
    int nwaves = (Jtot + 1) / 2;              // K = 2 tiles per wave
    int grid = (nwaves + (NTHR / 64) - 1) / (NTHR / 64);   // 2286

    mel_loss_main<<<grid, NTHR, 0, stream>>>(pred, tgt, mask, partial, BT, Jtot, grid);
    mel_loss_finalize<<<1, 640, 0, stream>>>(partial, w, (float*)d_out, grid);
}

// Round 7
// 194.307 us; speedup vs baseline: 1.0521x; 1.0013x over previous
//
#include <hip/hip_runtime.h>
#include <math.h>

#define D_MELS 80
#define F4ROW  (D_MELS/4)   // 20 float4 per row
#define T_DIM  4000
#define NQ     10
#define NTHR   256
#define RTILE  64           // main rows per tile
#define EROWS  (RTILE + 2)  // +2 halo rows (r-1, r-2 of tile base)
#define EPITCH 84           // padded LDS row pitch in floats (bank spread)

// quantities: 0=l1 1=band 2=diff2 3=tgt2 4=energy 5=mask 6=delta 7=dmask 8=delta2 9=d2mask

// Structure (R7): decouple load layout from compute layout via LDS.
//  phase 0: stage mask rows [rbase-2, rbase+64)
//  phase 1: stage e = pred - tgt for the tile, CONTIGUOUS 1KB wave loads
//           (full 128B line utilization by construction — fixes R6's +22MB
//            half-line L2-thrash refetch), accumulate tgt2 inline.
//  phase 2: (row,qtr) compute mapping reads own row + r-1 + r-2 from LDS —
//           deletes all cross-lane shuffles; masks gate halo/dead-row zeros.
__global__ __launch_bounds__(NTHR, 4) void mel_loss_main(
    const float* __restrict__ pred, const float* __restrict__ tgt,
    const float* __restrict__ mask,
    float* __restrict__ partial, int BT, int ntiles, int TPB, int nblk)
{
    __shared__ float e_lds[EROWS * EPITCH];
    __shared__ float smask[EROWS];
    __shared__ float red[NTHR / 64][NQ];

    const int tid  = threadIdx.x;
    const int lane = tid & 63;
    const int qtr  = lane & 3;          // float4-quarter pos within row reads
    const int rw   = lane >> 2;         // row within wave's 16-row slice
    const int wv   = tid >> 6;

    const float4* p4 = (const float4*)pred;
    const float4* q4 = (const float4*)tgt;

    float v_l1 = 0.f, v_band = 0.f, v_diff2 = 0.f, v_tgt2 = 0.f, v_energy = 0.f;
    float v_m = 0.f, v_d = 0.f, v_dm = 0.f, v_d2 = 0.f, v_d2m = 0.f;

    for (int it = 0; it < TPB; ++it) {
        const int tile = blockIdx.x * TPB + it;
        if (tile >= ntiles) break;
        const int rbase = tile * RTILE;

        if (it) __syncthreads();        // protect LDS reuse across tiles

        // ---- phase 0: mask rows ----
        if (tid < EROWS) {
            int r = rbase - 2 + tid;
            smask[tid] = (r >= 0 && r < BT) ? mask[r] : 0.f;
        }
        __syncthreads();

        // ---- phase 1: stage e, accumulate tgt2 ----
        // halo rows -> e-rows 0,1
        if (tid < 2 * F4ROW) {
            int hr = tid / F4ROW;       // 0,1  (global row rbase-2+hr)
            int hc = tid % F4ROW;
            int r  = rbase - 2 + hr;
            float4 ev = make_float4(0.f, 0.f, 0.f, 0.f);
            if (r >= 0 && r < BT && smask[hr] != 0.f) {
                float4 p = p4[(size_t)r * F4ROW + hc];
                float4 q = q4[(size_t)r * F4ROW + hc];
                ev = make_float4(p.x - q.x, p.y - q.y, p.z - q.z, p.w - q.w);
            }
            ((float4*)&e_lds[hr * EPITCH])[hc] = ev;
        }
        // main rows: wave reads 64 consecutive float4 = 1KB contiguous per load
        #pragma unroll 1
        for (int k = 0; k < 5; ++k) {
            int f4idx = tid + NTHR * k;             // 0..1279 over 64 rows
            int row   = f4idx / F4ROW;              // 0..63
            int col   = f4idx % F4ROW;
            int r     = rbase + row;
            float mval = smask[row + 2];
            float4 ev = make_float4(0.f, 0.f, 0.f, 0.f);
            if (r < BT && mval != 0.f) {            // dead/OOB rows stage zeros
                float4 p = p4[(size_t)r * F4ROW + col];
                float4 q = q4[(size_t)r * F4ROW + col];
                ev = make_float4(p.x - q.x, p.y - q.y, p.z - q.z, p.w - q.w);
                v_tgt2 += (q.x * q.x + q.y * q.y + q.z * q.z + q.w * q.w) * mval;
            }
            ((float4*)&e_lds[(row + 2) * EPITCH])[col] = ev;
        }
        __syncthreads();

        // ---- phase 2: compute from LDS, (row,qtr) mapping, no shuffles ----
        const int myrow = wv * 16 + rw;             // 0..63
        const float m = smask[myrow + 2];
        if (__any(m != 0.f)) {                      // wave-dead skip
            const int r = rbase + myrow;
            const float m1 = smask[myrow + 1];
            const float m2 = smask[myrow];
            const int t = r % T_DIM;
            const float mt   = (r < BT) ? m : 0.f;
            const float dmv  = (t >= 1) ? mt * m1 : 0.f;  // kills seq-boundary garbage
            const float d2mv = (t >= 2) ? dmv * m2 : 0.f;

            const float4* e0p = (const float4*)&e_lds[(myrow + 2) * EPITCH];
            const float4* e1p = (const float4*)&e_lds[(myrow + 1) * EPITCH];
            const float4* e2p = (const float4*)&e_lds[(myrow    ) * EPITCH];

            float l1r = 0.f, frr = 0.f, sqr = 0.f, er = 0.f, dr = 0.f, d2r = 0.f;
            #pragma unroll 1
            for (int k = 0; k < 5; ++k) {
                float4 e = e0p[qtr + 4 * k];
                float4 f = e1p[qtr + 4 * k];
                float4 g = e2p[qtr + 4 * k];

                float a0 = fabsf(e.x), a1 = fabsf(e.y), a2 = fabsf(e.z), a3 = fabsf(e.w);
                l1r += a0 + a1 + a2 + a3;
                // band extra (+1) on d in [10,50); d = 16k + 4qtr + c
                const int d0 = (k << 4) + (qtr << 2);
                frr += ((unsigned)(d0 + 0 - 10) < 40u ? a0 : 0.f)
                     + ((unsigned)(d0 + 1 - 10) < 40u ? a1 : 0.f)
                     + ((unsigned)(d0 + 2 - 10) < 40u ? a2 : 0.f)
                     + ((unsigned)(d0 + 3 - 10) < 40u ? a3 : 0.f);
                sqr += e.x * e.x + e.y * e.y + e.z * e.z + e.w * e.w;
                er  += e.x + e.y + e.z + e.w;
                dr  += fabsf(e.x - f.x) + fabsf(e.y - f.y)
                     + fabsf(e.z - f.z) + fabsf(e.w - f.w);
                d2r += fabsf(e.x - 2.f * f.x + g.x) + fabsf(e.y - 2.f * f.y + g.y)
                     + fabsf(e.z - 2.f * f.z + g.z) + fabsf(e.w - 2.f * f.w + g.w);
            }

            v_l1    += l1r * mt;
            v_band  += (l1r + frr) * mt;
            v_diff2 += sqr * mt;
            v_d     += dr * dmv;
            v_d2    += d2r * d2mv;

            // row-sum of e within the quad (4 lanes per row)
            er += __shfl_xor(er, 1, 64);
            er += __shfl_xor(er, 2, 64);
            if (qtr == 0) {
                v_energy += fabsf(er) * mt;
                v_m   += mt;
                v_dm  += dmv;
                v_d2m += d2mv;
            }
        }
    }

    // ---- block reduction: wave shuffle -> LDS -> per-block store (NO atomics) ----
    float vals[NQ] = {v_l1, v_band, v_diff2, v_tgt2, v_energy,
                      v_m, v_d, v_dm, v_d2, v_d2m};
    #pragma unroll
    for (int q = 0; q < NQ; ++q) {
        float v = vals[q];
        #pragma unroll
        for (int off = 32; off > 0; off >>= 1)
            v += __shfl_down(v, off, 64);
        vals[q] = v;
    }
    if (lane == 0) {
        #pragma unroll
        for (int q = 0; q < NQ; ++q) red[wv][q] = vals[q];
    }
    __syncthreads();
    if (tid < NQ) {
        float s = 0.f;
        #pragma unroll
        for (int wv2 = 0; wv2 < NTHR / 64; ++wv2) s += red[wv2][tid];
        partial[tid * nblk + blockIdx.x] = s;
    }
}

__global__ __launch_bounds__(640) void mel_loss_finalize(
    const float* __restrict__ partial, const float* __restrict__ w,
    float* __restrict__ out, int nblk)
{
    const int tid = threadIdx.x;
    const int wv  = tid >> 6;        // quantity index 0..9
    const int lane = tid & 63;
    __shared__ float fin[NQ];

    float s = 0.f;
    for (int i = lane; i < nblk; i += 64) s += partial[wv * nblk + i];
    #pragma unroll
    for (int off = 32; off > 0; off >>= 1) s += __shfl_down(s, off, 64);
    if (lane == 0 && wv < NQ) fin[wv] = s;
    __syncthreads();

    if (tid == 0) {
        float l1s = fin[0], bands = fin[1], diff2 = fin[2], tgt2 = fin[3];
        float energys = fin[4], ms = fin[5], ds = fin[6], dms = fin[7];
        float d2s = fin[8], d2ms = fin[9];

        float wsum = 0.f;
        for (int d = 0; d < D_MELS; ++d) wsum += w[d];
        float wmean = wsum / (float)D_MELS;

        float n1  = fmaxf(ms   * (float)D_MELS, 1.f);
        float nd  = fmaxf(dms  * (float)D_MELS, 1.f);
        float nd2 = fmaxf(d2ms * (float)D_MELS, 1.f);

        float l1_loss     = l1s / n1;
        float delta_loss  = ds / nd;
        float delta2_loss = d2s / nd2;
        float sc_num = sqrtf(diff2 / n1);
        float sc_den = fmaxf(sqrtf(tgt2 / n1), 1e-8f);
        float sc_loss = sc_num / sc_den;
        float band_loss = (bands / n1) / wmean;
        float energy_loss = (energys / (float)D_MELS) / fmaxf(ms, 1.f);

        out[0] = 1.0f * l1_loss + 0.5f * delta_loss + 0.25f * delta2_loss
               + 0.5f * sc_loss + 1.0f * band_loss + 0.5f * energy_loss;
    }
}

extern "C" void kernel_launch(void* const* d_in, const int* in_sizes, int n_in,
                              void* d_out, int out_size, void* d_ws, size_t ws_size,
                              hipStream_t stream) {
    const float* pred = (const float*)d_in[0];
    const float* tgt  = (const float*)d_in[1];
    const float* mask = (const float*)d_in[2];
    const float* w    = (const float*)d_in[3];
    int BT = in_sizes[2];                         // B*T = 256000
    float* partial = (float*)d_ws;                // NQ * grid floats

    int ntiles = (BT + RTILE - 1) / RTILE;        // 4000 64-row tiles
    int TPB = 2;                                  // tiles per block
    int grid = (ntiles + TPB - 1) / TPB;          // 2000
    // defensive: fit partial buffer into provided workspace
    while ((size_t)NQ * (size_t)grid * sizeof(float) > ws_size && TPB < ntiles) {
        TPB *= 2;
        grid = (ntiles + TPB - 1) / TPB;
    }

    mel_loss_main<<<grid, NTHR, 0, stream>>>(pred, tgt, mask, partial, BT, ntiles, TPB, grid);
    mel_loss_finalize<<<1, 640, 0, stream>>>(partial, w, (float*)d_out, grid);
}